// Round 5
// baseline (201.439 us; speedup 1.0000x reference)
//
#include <hip/hip_runtime.h>
#include <hip/hip_fp16.h>
#include <math.h>

#define N_NODES 50000
#define N_EDGES 800000
#define IN_CH 128
#define PROJ_CH 256   // HEADS*OUT_CH
#define OUT_CH 64
#define HEADS 4
#define NEG_SLOPE 0.2f
#define NREP 8           // one bucket replica per XCD (blockIdx & 7 ~ physical XCD)
#define CAP8 20          // per-replica capacity; per-replica degree ~ Poisson(2), P(>=20) ~ 1e-12
#define CAPT (NREP * CAP8)  // 160: total merged list bound in aggregate
#define SLOTS 208        // LDS slot stride; 208 % 32 == 16 -> exact 2-way bank aliasing (free)
#define PROJ_BLOCKS 782  // ceil(50000/64)
#define SCAT_BLOCKS 3125 // one edge per thread

typedef _Float16 f16x8 __attribute__((ext_vector_type(8)));
typedef _Float16 f16x4 __attribute__((ext_vector_type(4)));
typedef __fp16   hf2   __attribute__((ext_vector_type(2)));   // builtin-native packed half
typedef float    f32x4 __attribute__((ext_vector_type(4)));

__device__ __forceinline__ float leaky(float v) {
    return v > 0.f ? v : NEG_SLOPE * v;
}

__device__ __forceinline__ hf2 u32_as_h2(unsigned int u) {
    union { unsigned int u; hf2 h; } c; c.u = u; return c.h;
}

// Zeroes the 8 replica counters AND pre-converts W to fp16.
__global__ __launch_bounds__(256) void prep_kernel(
    const float* __restrict__ W, _Float16* __restrict__ Wh, int* __restrict__ cnt8)
{
    const int t = blockIdx.x * 256 + threadIdx.x;
    if (t < PROJ_CH * IN_CH) Wh[t] = (_Float16)W[t];
    if (t < NREP * N_NODES) cnt8[t] = 0;
}

// PURE SCATTER PROBE: one edge per thread, nothing else.
// 2 coalesced loads + 1 returning atomicAdd (XCD-local replica) + 1 random
// 2-byte store. Isolated so rocprof attributes its cost unambiguously.
__global__ __launch_bounds__(256) void scatter_kernel(
    const int* __restrict__ ei, int* __restrict__ cnt8, unsigned short* __restrict__ csr8)
{
    const int e = blockIdx.x * 256 + threadIdx.x;
    const int rep = blockIdx.x & (NREP - 1);
    const int esrc = ei[e];
    const int edst = ei[N_EDGES + e];
    const int pos = atomicAdd(&cnt8[rep * N_NODES + edst], 1);
    if (pos < CAP8) csr8[((size_t)rep * N_NODES + edst) * CAP8 + pos] = (unsigned short)esrc;
}

// GEMM-only: 64-node x 256-oc MFMA tile per block, 782 blocks.
__global__ __launch_bounds__(256) void proj_kernel(
    const float* __restrict__ x, const _Float16* __restrict__ Wh,
    const float* __restrict__ att_src, const float* __restrict__ att_dst,
    _Float16* __restrict__ h, float* __restrict__ a_src, float* __restrict__ a_dst)
{
    __shared__ _Float16 xs[64 * 136];
    const int tid = threadIdx.x;
    const int bid = blockIdx.x;

    const int w    = tid >> 6;
    const int lane = tid & 63;
    const int q    = lane >> 4;
    const int l15  = lane & 15;
    const int nb   = bid * 64;

    // x tile loads first (HBM, longest latency)
    float4 xv[8];
#pragma unroll
    for (int r = 0; r < 8; ++r) {
        int v   = r * 256 + tid;
        int row = v >> 5;
        int c4  = v & 31;
        int grow = nb + row;
        if (grow > N_NODES - 1) grow = N_NODES - 1;
        xv[r] = *(const float4*)(x + (size_t)grow * IN_CH + c4 * 4);
    }

    // B fragments: direct f16x8 loads from pre-converted W (L2-resident).
    // B[k = k0i*32 + q*8 + j][oc = w*64 + n0i*16 + l15]
    f16x8 B[4][4];
#pragma unroll
    for (int k0i = 0; k0i < 4; ++k0i)
#pragma unroll
        for (int n0i = 0; n0i < 4; ++n0i) {
            const int oc = w * 64 + n0i * 16 + l15;
            B[k0i][n0i] = *(const f16x8*)(Wh + (size_t)oc * IN_CH + k0i * 32 + q * 8);
        }

#pragma unroll
    for (int r = 0; r < 8; ++r) {
        int v   = r * 256 + tid;
        int row = v >> 5;
        int c4  = v & 31;
        f16x4 hv;
        hv[0] = (_Float16)xv[r].x; hv[1] = (_Float16)xv[r].y;
        hv[2] = (_Float16)xv[r].z; hv[3] = (_Float16)xv[r].w;
        *(f16x4*)&xs[row * 136 + c4 * 4] = hv;
    }
    __syncthreads();

    f32x4 acc[4][4];
#pragma unroll
    for (int m0i = 0; m0i < 4; ++m0i)
#pragma unroll
        for (int n0i = 0; n0i < 4; ++n0i)
            acc[m0i][n0i] = (f32x4){0.f, 0.f, 0.f, 0.f};

#pragma unroll
    for (int k0i = 0; k0i < 4; ++k0i) {
        f16x8 A[4];
#pragma unroll
        for (int m0i = 0; m0i < 4; ++m0i)
            A[m0i] = *(const f16x8*)&xs[(m0i * 16 + l15) * 136 + k0i * 32 + q * 8];
#pragma unroll
        for (int n0i = 0; n0i < 4; ++n0i)
#pragma unroll
            for (int m0i = 0; m0i < 4; ++m0i)
                acc[m0i][n0i] = __builtin_amdgcn_mfma_f32_16x16x32_f16(
                    A[m0i], B[k0i][n0i], acc[m0i][n0i], 0, 0, 0);
    }

    // epilogue: D row(node) = m0i*16 + q*4 + r, col = n0i*16 + l15
    float att_s[4], att_d[4];
#pragma unroll
    for (int n0i = 0; n0i < 4; ++n0i) {
        att_s[n0i] = att_src[w * 64 + n0i * 16 + l15];
        att_d[n0i] = att_dst[w * 64 + n0i * 16 + l15];
    }

#pragma unroll
    for (int m0i = 0; m0i < 4; ++m0i) {
        float vs[4], vd[4];
#pragma unroll
        for (int r = 0; r < 4; ++r) {
            float s = 0.f, d = 0.f;
#pragma unroll
            for (int n0i = 0; n0i < 4; ++n0i) {
                s = fmaf(acc[m0i][n0i][r], att_s[n0i], s);
                d = fmaf(acc[m0i][n0i][r], att_d[n0i], d);
            }
            vs[r] = s; vd[r] = d;
        }
#pragma unroll
        for (int off = 1; off < 16; off <<= 1) {
#pragma unroll
            for (int r = 0; r < 4; ++r) {
                vs[r] += __shfl_xor(vs[r], off, 64);
                vd[r] += __shfl_xor(vd[r], off, 64);
            }
        }
#pragma unroll
        for (int r = 0; r < 4; ++r) {
            int node = nb + m0i * 16 + q * 4 + r;
            if (l15 == 0 && node < N_NODES) {
                a_src[node * HEADS + w] = vs[r];
                a_dst[node * HEADS + w] = vd[r];
            }
        }
#pragma unroll
        for (int r = 0; r < 4; ++r) {
            int node = nb + m0i * 16 + q * 4 + r;
            if (node < N_NODES) {
#pragma unroll
                for (int n0i = 0; n0i < 4; ++n0i)
                    h[(size_t)node * PROJ_CH + w * 64 + n0i * 16 + l15] =
                        (_Float16)acc[m0i][n0i][r];
            }
        }
    }
}

// One WAVE per node. Phase 0: merge the 8 replica lists into LDS as pre-scaled
// byte offsets (j<<9). Phase 1: lane=(edge,head) exp -> [head][slot] weights
// (SLOTS=208 -> 2-way bank aliasing only); pads to a multiple of 8. Phase 2:
// 8 rows per iter (4 per half-wave, ILP-4 gathers), v_perm row-pairing +
// v_dot2_f32_f16 accumulation. 8-granularity cuts avg padded slots 24.6->20.9.
__global__ __launch_bounds__(256) void aggregate_kernel(
    const _Float16* __restrict__ h, const float* __restrict__ a_src,
    const float* __restrict__ a_dst, const int* __restrict__ cnt8,
    const unsigned short* __restrict__ csr8, const float* __restrict__ bias,
    float* __restrict__ out)
{
    const int tid  = threadIdx.x;
    const int wave = tid >> 6;
    const int l    = tid & 63;
    const int i    = blockIdx.x * 4 + wave;     // 12500 * 4 = 50000 exact

    __shared__ float lw_all[4][HEADS * SLOTS];  // [head][slot]
    __shared__ int   lj_all[4][SLOTS];          // scaled: j*512 (h row byte offset)
    float* lw = lw_all[wave];
    int*   lj = lj_all[wave];

    // phase 0: merge replica lists. All lanes load all 8 counts (same-address
    // broadcast loads) so each lane derives its own (nr_g, base_g) scalars.
    const int gr = l >> 3;      // replica this lane gathers from
    const int gk = l & 7;       // entry stride start
    int nr_g = 0, base_g = 0, m = 0;
#pragma unroll
    for (int r = 0; r < NREP; ++r) {
        int c = cnt8[r * N_NODES + i];
        c = min(c, CAP8);
        if (r == gr) { nr_g = c; base_g = m; }
        m += c;
    }
    if (l == 0) lj[0] = i << 9;
    {
        const size_t cbase = ((size_t)gr * N_NODES + i) * CAP8;
#pragma unroll
        for (int kk = 0; kk < CAP8; kk += 8) {
            int k = gk + kk;
            if (k < nr_g) lj[1 + base_g + k] = ((int)csr8[cbase + k]) << 9;
        }
    }

    const int h4   = l & 3;
    const float adh = a_dst[i * 4 + h4];
    const char* ab = (const char*)a_src;

    float lsum = 0.f;
    {
        float ws = __expf(leaky(a_src[i * 4 + h4] + adh));
        if (l < 4) { lw[l * SLOTS] = ws; lsum = ws; }
    }

    const int T  = m + 1;                 // slots incl. self
    const int Tp = (T + 7) & ~7;          // padded to 8
    const int erel = l >> 2;
    for (int s0 = 0; s0 < Tp - 1; s0 += 16) {
        const int e = s0 + erel;          // 0-based edge, slot = e+1 (max 176 < SLOTS)
        const bool valid = e < m;
        float w = 0.f;
        if (valid) {
            int sj = lj[e + 1];           // scaled j
            w = __expf(leaky(*(const float*)(ab + (sj >> 5) + h4 * 4) + adh));
        } else if (h4 == 0) {
            lj[e + 1] = 0;                // zero pad offsets (keep gathers in-bounds)
        }
        lsum += w;
        lw[h4 * SLOTS + e + 1] = w;
    }
#pragma unroll
    for (int off = 4; off < 64; off <<= 1) lsum += __shfl_xor(lsum, off, 64);

    __syncthreads();

    const int half_ = l >> 5;
    const int jj    = l & 31;
    const int hd    = jj >> 3;
    const unsigned jjb = (unsigned)jj * 16u;
    const char* hb = (const char*)h;
    const float* lwh = lw + hd * SLOTS;

    float acc[8];
#pragma unroll
    for (int k = 0; k < 8; ++k) acc[k] = 0.f;

    for (int qq = 0; qq < Tp; qq += 8) {
        const int eb = qq + 4 * half_;
        int o[4];
#pragma unroll
        for (int k = 0; k < 4; ++k) o[k] = lj[eb + k];
        uint4 d[4];
#pragma unroll
        for (int k = 0; k < 4; ++k)
            d[k] = *(const uint4*)(hb + ((unsigned)o[k] + jjb));

        hf2 wp[2];
#pragma unroll
        for (int pr = 0; pr < 2; ++pr) {
            float2 wf = *(const float2*)&lwh[eb + 2 * pr];
            wp[pr] = __builtin_amdgcn_cvt_pkrtz(wf.x, wf.y);
        }

#pragma unroll
        for (int pr = 0; pr < 2; ++pr) {
            const unsigned int* Aa = (const unsigned int*)&d[2 * pr];
            const unsigned int* Ab = (const unsigned int*)&d[2 * pr + 1];
#pragma unroll
            for (int k = 0; k < 4; ++k) {
                // pair rows (2pr, 2pr+1): lo = (ra_lo, rb_lo), hi = (ra_hi, rb_hi)
                unsigned int lo = __builtin_amdgcn_perm(Ab[k], Aa[k], 0x05040100u);
                unsigned int hi = __builtin_amdgcn_perm(Ab[k], Aa[k], 0x07060302u);
                acc[2 * k]     = __builtin_amdgcn_fdot2(u32_as_h2(lo), wp[pr], acc[2 * k], false);
                acc[2 * k + 1] = __builtin_amdgcn_fdot2(u32_as_h2(hi), wp[pr], acc[2 * k + 1], false);
            }
        }
    }

#pragma unroll
    for (int k = 0; k < 8; ++k) acc[k] += __shfl_xor(acc[k], 32, 64);

    float linv = 1.f / __shfl(lsum, hd, 64);
#pragma unroll
    for (int k = 0; k < 8; ++k) {
        float r = acc[k] * linv;
        r += __shfl_xor(r, 8, 64);
        r += __shfl_xor(r, 16, 64);
        acc[k] = r;
    }

    if (l < 8) {
        float* op = out + (size_t)i * OUT_CH + l * 8;
        float4 o0, o1;
        o0.x = fmaxf(0.25f * acc[0] + bias[l * 8 + 0], 0.f);
        o0.y = fmaxf(0.25f * acc[1] + bias[l * 8 + 1], 0.f);
        o0.z = fmaxf(0.25f * acc[2] + bias[l * 8 + 2], 0.f);
        o0.w = fmaxf(0.25f * acc[3] + bias[l * 8 + 3], 0.f);
        o1.x = fmaxf(0.25f * acc[4] + bias[l * 8 + 4], 0.f);
        o1.y = fmaxf(0.25f * acc[5] + bias[l * 8 + 5], 0.f);
        o1.z = fmaxf(0.25f * acc[6] + bias[l * 8 + 6], 0.f);
        o1.w = fmaxf(0.25f * acc[7] + bias[l * 8 + 7], 0.f);
        *(float4*)op = o0;
        *((float4*)op + 1) = o1;
    }
}

extern "C" void kernel_launch(void* const* d_in, const int* in_sizes, int n_in,
                              void* d_out, int out_size, void* d_ws, size_t ws_size,
                              hipStream_t stream)
{
    const float* x       = (const float*)d_in[0];
    const int*   ei      = (const int*)d_in[1];
    const float* W       = (const float*)d_in[2];
    const float* att_src = (const float*)d_in[3];
    const float* att_dst = (const float*)d_in[4];
    const float* bias    = (const float*)d_in[5];
    float* out = (float*)d_out;

    // workspace layout
    _Float16* h  = (_Float16*)d_ws;                             // N*256 fp16        25.6 MB
    float* asrc  = (float*)(h + (size_t)N_NODES * PROJ_CH);     // N*4                0.8 MB
    float* adst  = asrc + (size_t)N_NODES * HEADS;              // N*4                0.8 MB
    int*   cnt8  = (int*)(adst + (size_t)N_NODES * HEADS);      // 8*N                1.6 MB
    unsigned short* csr8 = (unsigned short*)(cnt8 + NREP * N_NODES); // 8*N*CAP8 u16 16.0 MB
    _Float16* Wh = (_Float16*)(csr8 + (size_t)NREP * N_NODES * CAP8); // 256*128 fp16 64 KB

    hipLaunchKernelGGL(prep_kernel, dim3((NREP * N_NODES + 255) / 256), dim3(256), 0, stream,
                       W, Wh, cnt8);
    hipLaunchKernelGGL(scatter_kernel, dim3(SCAT_BLOCKS), dim3(256), 0, stream,
                       ei, cnt8, csr8);
    hipLaunchKernelGGL(proj_kernel, dim3(PROJ_BLOCKS), dim3(256), 0, stream,
                       x, Wh, att_src, att_dst, h, asrc, adst);
    hipLaunchKernelGGL(aggregate_kernel, dim3(N_NODES / 4), dim3(256), 0, stream,
                       h, asrc, adst, cnt8, csr8, bias, out);
}

// Round 6
// 201.310 us; speedup vs baseline: 1.0006x; 1.0006x over previous
//
#include <hip/hip_runtime.h>
#include <hip/hip_fp16.h>
#include <math.h>

#define N_NODES 50000
#define N_EDGES 800000
#define IN_CH 128
#define PROJ_CH 256   // HEADS*OUT_CH
#define OUT_CH 64
#define HEADS 4
#define NEG_SLOPE 0.2f
#define NREP 8           // one bucket replica per XCD (blockIdx & 7 ~ physical XCD)
#define CAP8 20          // per-replica capacity; per-replica degree ~ Poisson(2), P(>=20) ~ 1e-12
#define CAPT (NREP * CAP8)  // 160: total merged list bound in aggregate
#define SLOTS 208        // LDS slot stride; 208 % 32 == 16 -> exact 2-way bank aliasing (free)
#define PROJ_BLOCKS 782  // ceil(50000/64)
#define SCAT_BLOCKS 3125 // one edge per thread

typedef _Float16 f16x8 __attribute__((ext_vector_type(8)));
typedef _Float16 f16x4 __attribute__((ext_vector_type(4)));
typedef __fp16   hf2   __attribute__((ext_vector_type(2)));   // builtin-native packed half
typedef float    f32x4 __attribute__((ext_vector_type(4)));

__device__ __forceinline__ float leaky(float v) {
    return v > 0.f ? v : NEG_SLOPE * v;
}

__device__ __forceinline__ hf2 u32_as_h2(unsigned int u) {
    union { unsigned int u; hf2 h; } c; c.u = u; return c.h;
}

// Zeroes the 8 replica counters AND pre-converts W to fp16.
__global__ __launch_bounds__(256) void prep_kernel(
    const float* __restrict__ W, _Float16* __restrict__ Wh, int* __restrict__ cnt8)
{
    const int t = blockIdx.x * 256 + threadIdx.x;
    if (t < PROJ_CH * IN_CH) Wh[t] = (_Float16)W[t];
    if (t < NREP * N_NODES) cnt8[t] = 0;
}

// PURE SCATTER PROBE: one edge per thread, nothing else (unchanged control).
__global__ __launch_bounds__(256) void scatter_kernel(
    const int* __restrict__ ei, int* __restrict__ cnt8, unsigned short* __restrict__ csr8)
{
    const int e = blockIdx.x * 256 + threadIdx.x;
    const int rep = blockIdx.x & (NREP - 1);
    const int esrc = ei[e];
    const int edst = ei[N_EDGES + e];
    const int pos = atomicAdd(&cnt8[rep * N_NODES + edst], 1);
    if (pos < CAP8) csr8[((size_t)rep * N_NODES + edst) * CAP8 + pos] = (unsigned short)esrc;
}

// GEMM-only: 64-node x 256-oc MFMA tile per block, 782 blocks (unchanged control).
__global__ __launch_bounds__(256) void proj_kernel(
    const float* __restrict__ x, const _Float16* __restrict__ Wh,
    const float* __restrict__ att_src, const float* __restrict__ att_dst,
    _Float16* __restrict__ h, float* __restrict__ a_src, float* __restrict__ a_dst)
{
    __shared__ _Float16 xs[64 * 136];
    const int tid = threadIdx.x;
    const int bid = blockIdx.x;

    const int w    = tid >> 6;
    const int lane = tid & 63;
    const int q    = lane >> 4;
    const int l15  = lane & 15;
    const int nb   = bid * 64;

    // x tile loads first (HBM, longest latency)
    float4 xv[8];
#pragma unroll
    for (int r = 0; r < 8; ++r) {
        int v   = r * 256 + tid;
        int row = v >> 5;
        int c4  = v & 31;
        int grow = nb + row;
        if (grow > N_NODES - 1) grow = N_NODES - 1;
        xv[r] = *(const float4*)(x + (size_t)grow * IN_CH + c4 * 4);
    }

    // B fragments: direct f16x8 loads from pre-converted W (L2-resident).
    // B[k = k0i*32 + q*8 + j][oc = w*64 + n0i*16 + l15]
    f16x8 B[4][4];
#pragma unroll
    for (int k0i = 0; k0i < 4; ++k0i)
#pragma unroll
        for (int n0i = 0; n0i < 4; ++n0i) {
            const int oc = w * 64 + n0i * 16 + l15;
            B[k0i][n0i] = *(const f16x8*)(Wh + (size_t)oc * IN_CH + k0i * 32 + q * 8);
        }

#pragma unroll
    for (int r = 0; r < 8; ++r) {
        int v   = r * 256 + tid;
        int row = v >> 5;
        int c4  = v & 31;
        f16x4 hv;
        hv[0] = (_Float16)xv[r].x; hv[1] = (_Float16)xv[r].y;
        hv[2] = (_Float16)xv[r].z; hv[3] = (_Float16)xv[r].w;
        *(f16x4*)&xs[row * 136 + c4 * 4] = hv;
    }
    __syncthreads();

    f32x4 acc[4][4];
#pragma unroll
    for (int m0i = 0; m0i < 4; ++m0i)
#pragma unroll
        for (int n0i = 0; n0i < 4; ++n0i)
            acc[m0i][n0i] = (f32x4){0.f, 0.f, 0.f, 0.f};

#pragma unroll
    for (int k0i = 0; k0i < 4; ++k0i) {
        f16x8 A[4];
#pragma unroll
        for (int m0i = 0; m0i < 4; ++m0i)
            A[m0i] = *(const f16x8*)&xs[(m0i * 16 + l15) * 136 + k0i * 32 + q * 8];
#pragma unroll
        for (int n0i = 0; n0i < 4; ++n0i)
#pragma unroll
            for (int m0i = 0; m0i < 4; ++m0i)
                acc[m0i][n0i] = __builtin_amdgcn_mfma_f32_16x16x32_f16(
                    A[m0i], B[k0i][n0i], acc[m0i][n0i], 0, 0, 0);
    }

    // epilogue: D row(node) = m0i*16 + q*4 + r, col = n0i*16 + l15
    float att_s[4], att_d[4];
#pragma unroll
    for (int n0i = 0; n0i < 4; ++n0i) {
        att_s[n0i] = att_src[w * 64 + n0i * 16 + l15];
        att_d[n0i] = att_dst[w * 64 + n0i * 16 + l15];
    }

#pragma unroll
    for (int m0i = 0; m0i < 4; ++m0i) {
        float vs[4], vd[4];
#pragma unroll
        for (int r = 0; r < 4; ++r) {
            float s = 0.f, d = 0.f;
#pragma unroll
            for (int n0i = 0; n0i < 4; ++n0i) {
                s = fmaf(acc[m0i][n0i][r], att_s[n0i], s);
                d = fmaf(acc[m0i][n0i][r], att_d[n0i], d);
            }
            vs[r] = s; vd[r] = d;
        }
#pragma unroll
        for (int off = 1; off < 16; off <<= 1) {
#pragma unroll
            for (int r = 0; r < 4; ++r) {
                vs[r] += __shfl_xor(vs[r], off, 64);
                vd[r] += __shfl_xor(vd[r], off, 64);
            }
        }
#pragma unroll
        for (int r = 0; r < 4; ++r) {
            int node = nb + m0i * 16 + q * 4 + r;
            if (l15 == 0 && node < N_NODES) {
                a_src[node * HEADS + w] = vs[r];
                a_dst[node * HEADS + w] = vd[r];
            }
        }
#pragma unroll
        for (int r = 0; r < 4; ++r) {
            int node = nb + m0i * 16 + q * 4 + r;
            if (node < N_NODES) {
#pragma unroll
                for (int n0i = 0; n0i < 4; ++n0i)
                    h[(size_t)node * PROJ_CH + w * 64 + n0i * 16 + l15] =
                        (_Float16)acc[m0i][n0i][r];
            }
        }
    }
}

// One WAVE per node. Phase 2 is now SOFTWARE-PIPELINED: iteration i+1's 4
// gathers are issued before iteration i's data is consumed (2-stage double
// buffer, branch-free dummy prefetch on the last iteration), so the ~100cyc
// of fdot2/perm work overlaps the L2/L3 gather latency.
__global__ __launch_bounds__(256) void aggregate_kernel(
    const _Float16* __restrict__ h, const float* __restrict__ a_src,
    const float* __restrict__ a_dst, const int* __restrict__ cnt8,
    const unsigned short* __restrict__ csr8, const float* __restrict__ bias,
    float* __restrict__ out)
{
    const int tid  = threadIdx.x;
    const int wave = tid >> 6;
    const int l    = tid & 63;
    const int i    = blockIdx.x * 4 + wave;     // 12500 * 4 = 50000 exact

    __shared__ float lw_all[4][HEADS * SLOTS];  // [head][slot]
    __shared__ int   lj_all[4][SLOTS];          // scaled: j*512 (h row byte offset)
    float* lw = lw_all[wave];
    int*   lj = lj_all[wave];

    // phase 0: merge replica lists (broadcast count loads -> per-lane scalars).
    const int gr = l >> 3;      // replica this lane gathers from
    const int gk = l & 7;       // entry stride start
    int nr_g = 0, base_g = 0, m = 0;
#pragma unroll
    for (int r = 0; r < NREP; ++r) {
        int c = cnt8[r * N_NODES + i];
        c = min(c, CAP8);
        if (r == gr) { nr_g = c; base_g = m; }
        m += c;
    }
    if (l == 0) lj[0] = i << 9;
    {
        const size_t cbase = ((size_t)gr * N_NODES + i) * CAP8;
#pragma unroll
        for (int kk = 0; kk < CAP8; kk += 8) {
            int k = gk + kk;
            if (k < nr_g) lj[1 + base_g + k] = ((int)csr8[cbase + k]) << 9;
        }
    }

    const int h4   = l & 3;
    const float adh = a_dst[i * 4 + h4];
    const char* ab = (const char*)a_src;

    float lsum = 0.f;
    {
        float ws = __expf(leaky(a_src[i * 4 + h4] + adh));
        if (l < 4) { lw[l * SLOTS] = ws; lsum = ws; }
    }

    const int T  = m + 1;                 // slots incl. self
    const int Tp = (T + 7) & ~7;          // padded to 8 (>= 8 always)
    const int erel = l >> 2;
    for (int s0 = 0; s0 < Tp - 1; s0 += 16) {
        const int e = s0 + erel;          // 0-based edge, slot = e+1 (max 176 < SLOTS)
        const bool valid = e < m;
        float w = 0.f;
        if (valid) {
            int sj = lj[e + 1];           // scaled j
            w = __expf(leaky(*(const float*)(ab + (sj >> 5) + h4 * 4) + adh));
        } else if (h4 == 0) {
            lj[e + 1] = 0;                // zero pad offsets (keep gathers in-bounds)
        }
        lsum += w;
        lw[h4 * SLOTS + e + 1] = w;
    }
#pragma unroll
    for (int off = 4; off < 64; off <<= 1) lsum += __shfl_xor(lsum, off, 64);

    __syncthreads();

    const int half_ = l >> 5;
    const int jj    = l & 31;
    const int hd    = jj >> 3;
    const unsigned jjb = (unsigned)jj * 16u;
    const char* hb = (const char*)h;
    const float* lwh = lw + hd * SLOTS;
    const int eb0 = 4 * half_;

    float acc[8];
#pragma unroll
    for (int k = 0; k < 8; ++k) acc[k] = 0.f;

    // pipeline prologue: issue iteration-0 gathers
    uint4 dcur0, dcur1, dcur2, dcur3;
    {
        int o0 = lj[eb0 + 0], o1 = lj[eb0 + 1], o2 = lj[eb0 + 2], o3 = lj[eb0 + 3];
        dcur0 = *(const uint4*)(hb + ((unsigned)o0 + jjb));
        dcur1 = *(const uint4*)(hb + ((unsigned)o1 + jjb));
        dcur2 = *(const uint4*)(hb + ((unsigned)o2 + jjb));
        dcur3 = *(const uint4*)(hb + ((unsigned)o3 + jjb));
    }

    for (int qq = 0; qq < Tp; qq += 8) {
        // prefetch next iteration's 4 rows (dummy re-read of slot block 0 on
        // the last iteration: branch-free, always in-bounds, L2-hot)
        const int ebn = (qq + 8 < Tp) ? (qq + 8 + 4 * half_) : eb0;
        int on0 = lj[ebn + 0], on1 = lj[ebn + 1], on2 = lj[ebn + 2], on3 = lj[ebn + 3];
        uint4 dn0 = *(const uint4*)(hb + ((unsigned)on0 + jjb));
        uint4 dn1 = *(const uint4*)(hb + ((unsigned)on1 + jjb));
        uint4 dn2 = *(const uint4*)(hb + ((unsigned)on2 + jjb));
        uint4 dn3 = *(const uint4*)(hb + ((unsigned)on3 + jjb));

        const int eb = qq + 4 * half_;
        hf2 wp[2];
#pragma unroll
        for (int pr = 0; pr < 2; ++pr) {
            float2 wf = *(const float2*)&lwh[eb + 2 * pr];
            wp[pr] = __builtin_amdgcn_cvt_pkrtz(wf.x, wf.y);
        }

        {
            const unsigned int* Aa = (const unsigned int*)&dcur0;
            const unsigned int* Ab = (const unsigned int*)&dcur1;
#pragma unroll
            for (int k = 0; k < 4; ++k) {
                unsigned int lo = __builtin_amdgcn_perm(Ab[k], Aa[k], 0x05040100u);
                unsigned int hi = __builtin_amdgcn_perm(Ab[k], Aa[k], 0x07060302u);
                acc[2 * k]     = __builtin_amdgcn_fdot2(u32_as_h2(lo), wp[0], acc[2 * k], false);
                acc[2 * k + 1] = __builtin_amdgcn_fdot2(u32_as_h2(hi), wp[0], acc[2 * k + 1], false);
            }
        }
        {
            const unsigned int* Aa = (const unsigned int*)&dcur2;
            const unsigned int* Ab = (const unsigned int*)&dcur3;
#pragma unroll
            for (int k = 0; k < 4; ++k) {
                unsigned int lo = __builtin_amdgcn_perm(Ab[k], Aa[k], 0x05040100u);
                unsigned int hi = __builtin_amdgcn_perm(Ab[k], Aa[k], 0x07060302u);
                acc[2 * k]     = __builtin_amdgcn_fdot2(u32_as_h2(lo), wp[1], acc[2 * k], false);
                acc[2 * k + 1] = __builtin_amdgcn_fdot2(u32_as_h2(hi), wp[1], acc[2 * k + 1], false);
            }
        }

        dcur0 = dn0; dcur1 = dn1; dcur2 = dn2; dcur3 = dn3;
    }

#pragma unroll
    for (int k = 0; k < 8; ++k) acc[k] += __shfl_xor(acc[k], 32, 64);

    float linv = 1.f / __shfl(lsum, hd, 64);
#pragma unroll
    for (int k = 0; k < 8; ++k) {
        float r = acc[k] * linv;
        r += __shfl_xor(r, 8, 64);
        r += __shfl_xor(r, 16, 64);
        acc[k] = r;
    }

    if (l < 8) {
        float* op = out + (size_t)i * OUT_CH + l * 8;
        float4 o0, o1;
        o0.x = fmaxf(0.25f * acc[0] + bias[l * 8 + 0], 0.f);
        o0.y = fmaxf(0.25f * acc[1] + bias[l * 8 + 1], 0.f);
        o0.z = fmaxf(0.25f * acc[2] + bias[l * 8 + 2], 0.f);
        o0.w = fmaxf(0.25f * acc[3] + bias[l * 8 + 3], 0.f);
        o1.x = fmaxf(0.25f * acc[4] + bias[l * 8 + 4], 0.f);
        o1.y = fmaxf(0.25f * acc[5] + bias[l * 8 + 5], 0.f);
        o1.z = fmaxf(0.25f * acc[6] + bias[l * 8 + 6], 0.f);
        o1.w = fmaxf(0.25f * acc[7] + bias[l * 8 + 7], 0.f);
        *(float4*)op = o0;
        *((float4*)op + 1) = o1;
    }
}

extern "C" void kernel_launch(void* const* d_in, const int* in_sizes, int n_in,
                              void* d_out, int out_size, void* d_ws, size_t ws_size,
                              hipStream_t stream)
{
    const float* x       = (const float*)d_in[0];
    const int*   ei      = (const int*)d_in[1];
    const float* W       = (const float*)d_in[2];
    const float* att_src = (const float*)d_in[3];
    const float* att_dst = (const float*)d_in[4];
    const float* bias    = (const float*)d_in[5];
    float* out = (float*)d_out;

    // workspace layout
    _Float16* h  = (_Float16*)d_ws;                             // N*256 fp16        25.6 MB
    float* asrc  = (float*)(h + (size_t)N_NODES * PROJ_CH);     // N*4                0.8 MB
    float* adst  = asrc + (size_t)N_NODES * HEADS;              // N*4                0.8 MB
    int*   cnt8  = (int*)(adst + (size_t)N_NODES * HEADS);      // 8*N                1.6 MB
    unsigned short* csr8 = (unsigned short*)(cnt8 + NREP * N_NODES); // 8*N*CAP8 u16 16.0 MB
    _Float16* Wh = (_Float16*)(csr8 + (size_t)NREP * N_NODES * CAP8); // 256*128 fp16 64 KB

    hipLaunchKernelGGL(prep_kernel, dim3((NREP * N_NODES + 255) / 256), dim3(256), 0, stream,
                       W, Wh, cnt8);
    hipLaunchKernelGGL(scatter_kernel, dim3(SCAT_BLOCKS), dim3(256), 0, stream,
                       ei, cnt8, csr8);
    hipLaunchKernelGGL(proj_kernel, dim3(PROJ_BLOCKS), dim3(256), 0, stream,
                       x, Wh, att_src, att_dst, h, asrc, adst);
    hipLaunchKernelGGL(aggregate_kernel, dim3(N_NODES / 4), dim3(256), 0, stream,
                       h, asrc, adst, cnt8, csr8, bias, out);
}